// Round 3
// baseline (157.681 us; speedup 1.0000x reference)
//
#include <hip/hip_runtime.h>
#include <math.h>

static constexpr int Nb = 32;    // batch
static constexpr int Cc = 512;   // channels
static constexpr int Ss = 1024;  // spatial
static constexpr int Kk = 64;    // clusters
static constexpr int Dd = 256;   // out dim

typedef __attribute__((ext_vector_type(8))) short bf16x8;
typedef __attribute__((ext_vector_type(4))) float f32x4;
typedef __attribute__((ext_vector_type(4))) unsigned int u32x4;

union FragU { u32x4 u; bf16x8 h; };

// pack bf16-truncations of (x0,x1) into one dword: hi16(x1)<<16 | hi16(x0)
__device__ __forceinline__ unsigned hi_pack(float x0, float x1) {
    return __builtin_amdgcn_perm(__float_as_uint(x1), __float_as_uint(x0), 0x07060302u);
}
__device__ __forceinline__ float trunc_hi(float x) {
    return __uint_as_float(__float_as_uint(x) & 0xFFFF0000u);
}
// split 8 f32 into hi/lo bf16x8 fragments
__device__ __forceinline__ void split8(const float* xv, FragU& bh, FragU& bl) {
#pragma unroll
    for (int p = 0; p < 4; ++p) {
        bh.u[p] = hi_pack(xv[2*p], xv[2*p+1]);
        float l0 = xv[2*p]   - trunc_hi(xv[2*p]);
        float l1 = xv[2*p+1] - trunc_hi(xv[2*p+1]);
        bl.u[p] = hi_pack(l0, l1);
    }
}

// ---------------------------------------------------------------------------
// prep: split conv_w (64x512 f32) into bf16 hi/lo. 8192 threads x 4 elems.
// ---------------------------------------------------------------------------
__global__ __launch_bounds__(256) void kprep_cw(
    const float* __restrict__ cw, short* __restrict__ cwh, short* __restrict__ cwl)
{
    int t = blockIdx.x * 256 + threadIdx.x;
    float4 v = *(const float4*)&cw[4 * (size_t)t];
    unsigned h0 = hi_pack(v.x, v.y), h1 = hi_pack(v.z, v.w);
    float l0 = v.x - trunc_hi(v.x), l1 = v.y - trunc_hi(v.y);
    float l2 = v.z - trunc_hi(v.z), l3 = v.w - trunc_hi(v.w);
    unsigned g0 = hi_pack(l0, l1), g1 = hi_pack(l2, l3);
    ((uint2*)cwh)[t] = make_uint2(h0, h1);
    ((uint2*)cwl)[t] = make_uint2(g0, g1);
}

// ---------------------------------------------------------------------------
// K1 (MFMA): scores[k][s] = sum_c w[k][c] x[c][s]; inv-norm from the same x
// loads; in-register softmax over k; writes a' = softmax * inv_norm as
// bf16 hi/lo, plus asum partials (pre-fold sums of a).
// grid (16 stiles, 32 n), block 256 (4 waves; wave w owns s-cols 16w..16w+15).
// ---------------------------------------------------------------------------
__global__ __launch_bounds__(256) void k1_sa(
    const float* __restrict__ x, const short* __restrict__ cw_hi,
    const short* __restrict__ cw_lo, short* __restrict__ a_hi,
    short* __restrict__ a_lo, float* __restrict__ asum_part)
{
    const int tid = threadIdx.x;
    const int w = tid >> 6, lane = tid & 63;
    const int l15 = lane & 15, lg = lane >> 4;
    const int n = blockIdx.y, s0 = blockIdx.x * 64;
    const int scol = s0 + 16 * w + l15;        // this lane's s column

    f32x4 zero4 = {0.f, 0.f, 0.f, 0.f};
    f32x4 acc[4] = {zero4, zero4, zero4, zero4};
    float ssq = 0.f;

    const float* xcol = x + (size_t)n * Cc * Ss + scol;

#pragma unroll 2
    for (int ct = 0; ct < 16; ++ct) {
        const int cb = ct * 32 + 8 * lg;       // K-dim (=c) base for this lane
        float xv[8];
#pragma unroll
        for (int j = 0; j < 8; ++j) xv[j] = xcol[(size_t)(cb + j) * Ss];
#pragma unroll
        for (int j = 0; j < 8; ++j) ssq += xv[j] * xv[j];
        FragU bh, bl;
        split8(xv, bh, bl);
#pragma unroll
        for (int m = 0; m < 4; ++m) {
            FragU ah, al;
            const int row = 16 * m + l15;
            ah.u = *(const u32x4*)&cw_hi[(size_t)row * Cc + cb];
            al.u = *(const u32x4*)&cw_lo[(size_t)row * Cc + cb];
            acc[m] = __builtin_amdgcn_mfma_f32_16x16x32_bf16(al.h, bh.h, acc[m], 0, 0, 0);
            acc[m] = __builtin_amdgcn_mfma_f32_16x16x32_bf16(ah.h, bl.h, acc[m], 0, 0, 0);
            acc[m] = __builtin_amdgcn_mfma_f32_16x16x32_bf16(ah.h, bh.h, acc[m], 0, 0, 0);
        }
    }

    // per-s inverse L2 norm (4 lane-groups covered disjoint c ranges)
    ssq += __shfl_xor(ssq, 16);
    ssq += __shfl_xor(ssq, 32);
    const float inv = 1.f / fmaxf(sqrtf(ssq), 1e-12f);

    // softmax over k=64 per s-col: 16 in-lane values + lanes {l,l^16,l^32,l^48}
    float sv[4][4];
    float mmax = -1e30f;
#pragma unroll
    for (int m = 0; m < 4; ++m)
#pragma unroll
        for (int r = 0; r < 4; ++r) {
            sv[m][r] = acc[m][r] * inv;
            mmax = fmaxf(mmax, sv[m][r]);
        }
    mmax = fmaxf(mmax, __shfl_xor(mmax, 16));
    mmax = fmaxf(mmax, __shfl_xor(mmax, 32));
    float den = 0.f;
#pragma unroll
    for (int m = 0; m < 4; ++m)
#pragma unroll
        for (int r = 0; r < 4; ++r) {
            sv[m][r] = expf(sv[m][r] - mmax);
            den += sv[m][r];
        }
    den += __shfl_xor(den, 16);
    den += __shfl_xor(den, 32);
    const float rinv = 1.f / den;

#pragma unroll
    for (int m = 0; m < 4; ++m)
#pragma unroll
        for (int r = 0; r < 4; ++r) {
            const float a = sv[m][r] * rinv;
            const int k = 16 * m + 4 * lg + r;   // D: row=(lane>>4)*4+reg
            // asum over the wave's 16 s-cols (pre-fold value)
            float t = a;
            t += __shfl_xor(t, 1); t += __shfl_xor(t, 2);
            t += __shfl_xor(t, 4); t += __shfl_xor(t, 8);
            if (l15 == 0)
                asum_part[((size_t)(n * Kk + k) << 6) + blockIdx.x * 4 + w] = t;
            // a' = a * inv_norm, split to bf16 hi/lo
            const float av = a * inv;
            const unsigned u = __float_as_uint(av);
            const float hv = __uint_as_float(u & 0xFFFF0000u);
            const size_t idx = (size_t)(n * Kk + k) * Ss + scol;
            a_hi[idx] = (short)(u >> 16);
            a_lo[idx] = (short)(__float_as_uint(av - hv) >> 16);
        }
}

// ---------------------------------------------------------------------------
// K2 (MFMA): vlad_part[sh][n][k][c] = sum_{s in half} a'[k][s] x[c][s]
// (minus asum*centroid, folded into half 1). All frags direct from global.
// grid (32 n, 8 cpanels, 2 shalf), block 256 (wave w owns c-cols 16w..).
// ---------------------------------------------------------------------------
__global__ __launch_bounds__(256) void k2_vlad(
    const float* __restrict__ x, const short* __restrict__ a_hi,
    const short* __restrict__ a_lo, const float* __restrict__ centroids,
    const float* __restrict__ asum_part, float* __restrict__ vp0,
    float* __restrict__ vp1)
{
    __shared__ float asum_l[64];
    const int tid = threadIdx.x;
    const int w = tid >> 6, lane = tid & 63;
    const int l15 = lane & 15, lg = lane >> 4;
    const int n = blockIdx.x, cp = blockIdx.y, sh = blockIdx.z;

    if (tid < 64) {
        float s = 0.f;
        const float* ap = &asum_part[(size_t)(n * Kk + tid) << 6];
#pragma unroll
        for (int i = 0; i < 64; ++i) s += ap[i];
        asum_l[tid] = s;
    }
    __syncthreads();

    f32x4 zero4 = {0.f, 0.f, 0.f, 0.f};
    f32x4 acc[4] = {zero4, zero4, zero4, zero4};

    const int c = cp * 64 + 16 * w + l15;      // this lane's c column
    const float* xrow = x + (size_t)(n * Cc + c) * Ss + sh * 512;
    const short* ahb = a_hi + (size_t)n * Kk * Ss + sh * 512;
    const short* alb = a_lo + (size_t)n * Kk * Ss + sh * 512;

#pragma unroll 2
    for (int st = 0; st < 16; ++st) {
        const int so = st * 32 + 8 * lg;       // K-dim (=s) base for this lane
        float4 xa = *(const float4*)&xrow[so];
        float4 xb = *(const float4*)&xrow[so + 4];
        float xv[8] = {xa.x, xa.y, xa.z, xa.w, xb.x, xb.y, xb.z, xb.w};
        FragU bh, bl;
        split8(xv, bh, bl);
#pragma unroll
        for (int m = 0; m < 4; ++m) {
            FragU ah, al;
            const size_t ao = (size_t)(16 * m + l15) * Ss + so;
            ah.u = *(const u32x4*)&ahb[ao];
            al.u = *(const u32x4*)&alb[ao];
            acc[m] = __builtin_amdgcn_mfma_f32_16x16x32_bf16(al.h, bh.h, acc[m], 0, 0, 0);
            acc[m] = __builtin_amdgcn_mfma_f32_16x16x32_bf16(ah.h, bl.h, acc[m], 0, 0, 0);
            acc[m] = __builtin_amdgcn_mfma_f32_16x16x32_bf16(ah.h, bh.h, acc[m], 0, 0, 0);
        }
    }

    float* dst = sh ? vp1 : vp0;
#pragma unroll
    for (int m = 0; m < 4; ++m)
#pragma unroll
        for (int r = 0; r < 4; ++r) {
            const int k = 16 * m + 4 * lg + r;
            float val = acc[m][r];
            if (sh == 1) val -= asum_l[k] * centroids[(size_t)k * Cc + c];
            dst[(size_t)(n * Kk + k) * Cc + c] = val;
        }
}

// ---------------------------------------------------------------------------
// K3: vlad = vp0 + vp1 (in place into vp0), intra-norm + global norm -> scale
// grid 32 (n), block 512 (64 k x 8 lanes)
// ---------------------------------------------------------------------------
__global__ __launch_bounds__(512) void k3_scale(
    float* __restrict__ vlad, const float* __restrict__ vp1,
    float* __restrict__ scale)
{
    __shared__ float nrm_l[64];
    const int tid = threadIdx.x, n = blockIdx.x;
    const int k = tid >> 3, u = tid & 7;
    const size_t base = (size_t)(n * Kk + k) * Cc + u * 64;
    float ssq = 0.f;
#pragma unroll
    for (int i = 0; i < 16; ++i) {
        float4 v0 = *(const float4*)&vlad[base + 4 * i];
        float4 v1 = *(const float4*)&vp1[base + 4 * i];
        float4 s;
        s.x = v0.x + v1.x; s.y = v0.y + v1.y;
        s.z = v0.z + v1.z; s.w = v0.w + v1.w;
        *(float4*)&vlad[base + 4 * i] = s;
        ssq += s.x * s.x + s.y * s.y + s.z * s.z + s.w * s.w;
    }
    ssq += __shfl_xor(ssq, 1);
    ssq += __shfl_xor(ssq, 2);
    ssq += __shfl_xor(ssq, 4);
    if (u == 0) nrm_l[k] = sqrtf(ssq);
    __syncthreads();
    if (tid < 64) {
        float r = nrm_l[tid];
        float rn = r / fmaxf(r, 1e-12f);
        float p = rn * rn;
        for (int off = 32; off >= 1; off >>= 1) p += __shfl_xor(p, off);
        float g = sqrtf(p);
        scale[n * Kk + tid] = 1.f / (fmaxf(r, 1e-12f) * fmaxf(g, 1e-12f));
    }
}

// ---------------------------------------------------------------------------
// K4: partial v[n][d] over a kc-chunk of 128: vpart[chunk][n][d]
// ---------------------------------------------------------------------------
__global__ __launch_bounds__(256) void k4_hidden(
    const float* __restrict__ vlad, const float* __restrict__ scale,
    const float* __restrict__ hw, float* __restrict__ vpart)
{
    __shared__ float vl[128][36];
    __shared__ float scale_l[32];
    const int tid = threadIdx.x;
    const int kc0 = blockIdx.x * 128;
    const int k = kc0 >> 9;             // chunk lies inside one k
    if (tid < 32) scale_l[tid] = scale[tid * Kk + k];
    __syncthreads();
#pragma unroll
    for (int i = 0; i < 16; ++i) {
        int idx = tid + i * 256;
        int nn = idx >> 7, kcl = idx & 127;
        vl[kcl][nn] = vlad[(size_t)nn * (Kk * Cc) + kc0 + kcl] * scale_l[nn];
    }
    __syncthreads();

    const int dq = tid & 63, nq = tid >> 6;
    float acc[4][8];
#pragma unroll
    for (int i = 0; i < 4; ++i)
#pragma unroll
        for (int j = 0; j < 8; ++j) acc[i][j] = 0.f;

    for (int kcl = 0; kcl < 128; ++kcl) {
        const float4 v0 = *(const float4*)&vl[kcl][nq * 8];
        const float4 v1 = *(const float4*)&vl[kcl][nq * 8 + 4];
        const float* wrow = &hw[(size_t)(kc0 + kcl) * Dd + dq];
#pragma unroll
        for (int dd = 0; dd < 4; ++dd) {
            float w = wrow[64 * dd];
            acc[dd][0] += w * v0.x; acc[dd][1] += w * v0.y;
            acc[dd][2] += w * v0.z; acc[dd][3] += w * v0.w;
            acc[dd][4] += w * v1.x; acc[dd][5] += w * v1.y;
            acc[dd][6] += w * v1.z; acc[dd][7] += w * v1.w;
        }
    }
#pragma unroll
    for (int dd = 0; dd < 4; ++dd)
#pragma unroll
        for (int j = 0; j < 8; ++j)
            vpart[((size_t)blockIdx.x * Nb + nq * 8 + j) * Dd + dq + 64 * dd] = acc[dd][j];
}

// ---------------------------------------------------------------------------
// K5a: reduce 256 partial chunks -> v[n][d]
// ---------------------------------------------------------------------------
__global__ __launch_bounds__(256) void k5a_reduce(
    const float* __restrict__ vpart, float* __restrict__ v)
{
    int flat = blockIdx.x * 256 + threadIdx.x;
    float s = 0.f;
#pragma unroll 8
    for (int ch = 0; ch < 256; ++ch) s += vpart[(size_t)ch * (Nb * Dd) + flat];
    v[flat] = s;
}

// ---------------------------------------------------------------------------
// K5b: BatchNorm over n (training stats, biased var, two-pass)
// ---------------------------------------------------------------------------
__global__ __launch_bounds__(256) void k5b_bn(
    const float* __restrict__ v, const float* __restrict__ gamma,
    const float* __restrict__ beta, float* __restrict__ v_bn)
{
    const int d = threadIdx.x;
    float vals[Nb];
    float s1 = 0.f;
#pragma unroll
    for (int n = 0; n < Nb; ++n) {
        vals[n] = v[n * Dd + d];
        s1 += vals[n];
    }
    float m = s1 * (1.f / Nb);
    float var = 0.f;
#pragma unroll
    for (int n = 0; n < Nb; ++n) {
        float t = vals[n] - m;
        var += t * t;
    }
    var *= (1.f / Nb);
    float inv = rsqrtf(var + 1e-5f);
    float g = gamma[d], b = beta[d];
#pragma unroll
    for (int n = 0; n < Nb; ++n)
        v_bn[n * Dd + d] = (vals[n] - m) * inv * g + b;
}

// ---------------------------------------------------------------------------
// K5c: g_raw = v_bn @ gating_w
// ---------------------------------------------------------------------------
__global__ __launch_bounds__(256) void k5c_gate(
    const float* __restrict__ v_bn, const float* __restrict__ gw,
    float* __restrict__ g_raw)
{
    __shared__ float vb[Dd];
    const int n = blockIdx.x, d = threadIdx.x;
    vb[d] = v_bn[n * Dd + d];
    __syncthreads();
    float acc = 0.f;
#pragma unroll 8
    for (int c = 0; c < Dd; ++c) acc += vb[c] * gw[c * Dd + d];
    g_raw[n * Dd + d] = acc;
}

// ---------------------------------------------------------------------------
// K5d: gbn BatchNorm + sigmoid + multiply -> out
// ---------------------------------------------------------------------------
__global__ __launch_bounds__(256) void k5d_out(
    const float* __restrict__ g_raw, const float* __restrict__ v_bn,
    const float* __restrict__ ggamma, const float* __restrict__ gbeta,
    float* __restrict__ out)
{
    const int d = threadIdx.x;
    float vals[Nb];
    float s1 = 0.f;
#pragma unroll
    for (int n = 0; n < Nb; ++n) {
        vals[n] = g_raw[n * Dd + d];
        s1 += vals[n];
    }
    float m = s1 * (1.f / Nb);
    float var = 0.f;
#pragma unroll
    for (int n = 0; n < Nb; ++n) {
        float t = vals[n] - m;
        var += t * t;
    }
    var *= (1.f / Nb);
    float inv = rsqrtf(var + 1e-5f);
    float g = ggamma[d], b = gbeta[d];
#pragma unroll
    for (int n = 0; n < Nb; ++n) {
        float t = (vals[n] - m) * inv * g + b;
        float sg = 1.f / (1.f + expf(-t));
        out[n * Dd + d] = v_bn[n * Dd + d] * sg;
    }
}

// ---------------------------------------------------------------------------
extern "C" void kernel_launch(void* const* d_in, const int* in_sizes, int n_in,
                              void* d_out, int out_size, void* d_ws, size_t ws_size,
                              hipStream_t stream)
{
    const float* x         = (const float*)d_in[0];
    const float* conv_w    = (const float*)d_in[1];
    const float* centroids = (const float*)d_in[2];
    const float* hidden_w  = (const float*)d_in[3];
    const float* bn2_gamma = (const float*)d_in[4];
    const float* bn2_beta  = (const float*)d_in[5];
    const float* gating_w  = (const float*)d_in[6];
    const float* gbn_gamma = (const float*)d_in[7];
    const float* gbn_beta  = (const float*)d_in[8];
    float* out = (float*)d_out;

    char* B = (char*)d_ws;
    short* a_hi      = (short*)(B);                          // 4 MB
    short* a_lo      = (short*)(B + (4u << 20));             // 4 MB
    float* vp0       = (float*)(B + (8u << 20));             // 4 MB (-> vlad)
    float* vp1       = (float*)(B + (12u << 20));            // 4 MB
    short* cw_hi     = (short*)(B + (16u << 20));            // 64 KB
    short* cw_lo     = (short*)(B + (16u << 20) + 65536u);   // 64 KB
    float* asum_part = (float*)(B + (16u << 20) + 131072u);  // 512 KB
    float* scale     = (float*)(B + (16u << 20) + 655360u);  // 8 KB
    float* v         = scale + 2048;
    float* v_bn      = v + 8192;
    float* g_raw     = v_bn + 8192;
    float* vpart     = (float*)B;   // alias a_hi/a_lo (dead after k2), 8 MB

    kprep_cw<<<32, 256, 0, stream>>>(conv_w, cw_hi, cw_lo);
    k1_sa<<<dim3(16, 32), 256, 0, stream>>>(x, cw_hi, cw_lo, a_hi, a_lo, asum_part);
    k2_vlad<<<dim3(32, 8, 2), 256, 0, stream>>>(x, a_hi, a_lo, centroids, asum_part, vp0, vp1);
    k3_scale<<<32, 512, 0, stream>>>(vp0, vp1, scale);
    k4_hidden<<<256, 256, 0, stream>>>(vp0, scale, hidden_w, vpart);
    k5a_reduce<<<32, 256, 0, stream>>>(vpart, v);
    k5b_bn<<<1, 256, 0, stream>>>(v, bn2_gamma, bn2_beta, v_bn);
    k5c_gate<<<32, 256, 0, stream>>>(v_bn, gating_w, g_raw);
    k5d_out<<<1, 256, 0, stream>>>(g_raw, v_bn, gbn_gamma, gbn_beta, out);
}

// Round 4
// 141.298 us; speedup vs baseline: 1.1159x; 1.1159x over previous
//
#include <hip/hip_runtime.h>
#include <math.h>

static constexpr int Nb = 32;    // batch
static constexpr int Cc = 512;   // channels
static constexpr int Ss = 1024;  // spatial
static constexpr int Kk = 64;    // clusters
static constexpr int Dd = 256;   // out dim

typedef __attribute__((ext_vector_type(8))) short bf16x8;
typedef __attribute__((ext_vector_type(4))) float f32x4;
typedef __attribute__((ext_vector_type(4))) unsigned int u32x4;

union FragU { u32x4 u; bf16x8 h; };

// pack bf16-truncations of (x0,x1) into one dword: hi16(x1)<<16 | hi16(x0)
__device__ __forceinline__ unsigned hi_pack(float x0, float x1) {
    return __builtin_amdgcn_perm(__float_as_uint(x1), __float_as_uint(x0), 0x07060302u);
}
__device__ __forceinline__ float trunc_hi(float x) {
    return __uint_as_float(__float_as_uint(x) & 0xFFFF0000u);
}
__device__ __forceinline__ void split8(const float* xv, FragU& bh, FragU& bl) {
#pragma unroll
    for (int p = 0; p < 4; ++p) {
        bh.u[p] = hi_pack(xv[2*p], xv[2*p+1]);
        float l0 = xv[2*p]   - trunc_hi(xv[2*p]);
        float l1 = xv[2*p+1] - trunc_hi(xv[2*p+1]);
        bl.u[p] = hi_pack(l0, l1);
    }
}

// ---------------------------------------------------------------------------
// prep: split conv_w (64x512 f32) into bf16 hi/lo.
// ---------------------------------------------------------------------------
__global__ __launch_bounds__(256) void kprep_cw(
    const float* __restrict__ cw, short* __restrict__ cwh, short* __restrict__ cwl)
{
    int t = blockIdx.x * 256 + threadIdx.x;
    float4 v = *(const float4*)&cw[4 * (size_t)t];
    unsigned h0 = hi_pack(v.x, v.y), h1 = hi_pack(v.z, v.w);
    float l0 = v.x - trunc_hi(v.x), l1 = v.y - trunc_hi(v.y);
    float l2 = v.z - trunc_hi(v.z), l3 = v.w - trunc_hi(v.w);
    unsigned g0 = hi_pack(l0, l1), g1 = hi_pack(l2, l3);
    ((uint2*)cwh)[t] = make_uint2(h0, h1);
    ((uint2*)cwl)[t] = make_uint2(g0, g1);
}

// ---------------------------------------------------------------------------
// K1 (MFMA, 8 waves): wave w: s-group wq=w&3, c-half wh=w>>2 (256 c each).
// Partial acc + ssq combined via LDS; waves 0-3 finish softmax + stores.
// grid (16 stiles, 32 n), block 512 -> 4096 waves = 4/SIMD.
// ---------------------------------------------------------------------------
__global__ __launch_bounds__(512) void k1_sa(
    const float* __restrict__ x, const short* __restrict__ cw_hi,
    const short* __restrict__ cw_lo, short* __restrict__ a_hi,
    short* __restrict__ a_lo, float* __restrict__ asum_part)
{
    __shared__ f32x4 comb[4][64][4];   // [wq][lane][m]
    __shared__ float combq[4][64];

    const int tid = threadIdx.x;
    const int w = tid >> 6, lane = tid & 63;
    const int wq = w & 3, wh = w >> 2;
    const int l15 = lane & 15, lg = lane >> 4;
    const int n = blockIdx.y, s0 = blockIdx.x * 64;
    const int scol = s0 + 16 * wq + l15;

    f32x4 zero4 = {0.f, 0.f, 0.f, 0.f};
    f32x4 acc[4] = {zero4, zero4, zero4, zero4};
    float ssq = 0.f;

    const float* xcol = x + (size_t)n * Cc * Ss + scol;

#pragma unroll 2
    for (int ct = 0; ct < 8; ++ct) {
        const int cb = wh * 256 + ct * 32 + 8 * lg;
        float xv[8];
#pragma unroll
        for (int j = 0; j < 8; ++j) xv[j] = xcol[(size_t)(cb + j) * Ss];
#pragma unroll
        for (int j = 0; j < 8; ++j) ssq += xv[j] * xv[j];
        FragU bh, bl;
        split8(xv, bh, bl);
#pragma unroll
        for (int m = 0; m < 4; ++m) {
            FragU ah, al;
            const int row = 16 * m + l15;
            ah.u = *(const u32x4*)&cw_hi[(size_t)row * Cc + cb];
            al.u = *(const u32x4*)&cw_lo[(size_t)row * Cc + cb];
            acc[m] = __builtin_amdgcn_mfma_f32_16x16x32_bf16(al.h, bh.h, acc[m], 0, 0, 0);
            acc[m] = __builtin_amdgcn_mfma_f32_16x16x32_bf16(ah.h, bl.h, acc[m], 0, 0, 0);
            acc[m] = __builtin_amdgcn_mfma_f32_16x16x32_bf16(ah.h, bh.h, acc[m], 0, 0, 0);
        }
    }

    if (wh == 1) {
#pragma unroll
        for (int m = 0; m < 4; ++m) comb[wq][lane][m] = acc[m];
        combq[wq][lane] = ssq;
    }
    __syncthreads();
    if (wh == 1) return;     // no further barriers below

#pragma unroll
    for (int m = 0; m < 4; ++m) acc[m] += comb[wq][lane][m];
    ssq += combq[wq][lane];

    // per-s inverse L2 norm (combine the 4 lane-groups' c-slices)
    ssq += __shfl_xor(ssq, 16);
    ssq += __shfl_xor(ssq, 32);
    const float inv = 1.f / fmaxf(sqrtf(ssq), 1e-12f);

    // softmax over k=64 per s-col
    float sv[4][4];
    float mmax = -1e30f;
#pragma unroll
    for (int m = 0; m < 4; ++m)
#pragma unroll
        for (int r = 0; r < 4; ++r) {
            sv[m][r] = acc[m][r] * inv;
            mmax = fmaxf(mmax, sv[m][r]);
        }
    mmax = fmaxf(mmax, __shfl_xor(mmax, 16));
    mmax = fmaxf(mmax, __shfl_xor(mmax, 32));
    float den = 0.f;
#pragma unroll
    for (int m = 0; m < 4; ++m)
#pragma unroll
        for (int r = 0; r < 4; ++r) {
            sv[m][r] = expf(sv[m][r] - mmax);
            den += sv[m][r];
        }
    den += __shfl_xor(den, 16);
    den += __shfl_xor(den, 32);
    const float rinv = 1.f / den;

#pragma unroll
    for (int m = 0; m < 4; ++m)
#pragma unroll
        for (int r = 0; r < 4; ++r) {
            const float a = sv[m][r] * rinv;
            const int k = 16 * m + 4 * lg + r;
            float t = a;
            t += __shfl_xor(t, 1); t += __shfl_xor(t, 2);
            t += __shfl_xor(t, 4); t += __shfl_xor(t, 8);
            if (l15 == 0)
                asum_part[((size_t)(n * Kk + k) << 6) + blockIdx.x * 4 + wq] = t;
            const float av = a * inv;
            const unsigned u = __float_as_uint(av);
            const float hv = __uint_as_float(u & 0xFFFF0000u);
            const size_t idx = (size_t)(n * Kk + k) * Ss + scol;
            a_hi[idx] = (short)(u >> 16);
            a_lo[idx] = (short)(__float_as_uint(av - hv) >> 16);
        }
}

// ---------------------------------------------------------------------------
// kasum: asum[n][k] = sum of 64 partials. 2048 rows, one thread each.
// ---------------------------------------------------------------------------
__global__ __launch_bounds__(256) void kasum(
    const float* __restrict__ asum_part, float* __restrict__ asum)
{
    int row = blockIdx.x * 256 + threadIdx.x;
    const float* p = &asum_part[(size_t)row << 6];
    float s = 0.f;
#pragma unroll
    for (int i = 0; i < 16; ++i) {
        float4 v = *(const float4*)&p[4 * i];
        s += v.x + v.y + v.z + v.w;
    }
    asum[row] = s;
}

// ---------------------------------------------------------------------------
// K2 (MFMA, 8 waves): wave w: c-group wq=w&3, s-quarter wh=w>>2 within the
// z-half. Partials combined via LDS; waves 0-3 store (z==1 folds centroid).
// grid (32 n, 8 cpanels, 2 shalf), block 512 -> 4/SIMD.
// ---------------------------------------------------------------------------
__global__ __launch_bounds__(512) void k2_vlad(
    const float* __restrict__ x, const short* __restrict__ a_hi,
    const short* __restrict__ a_lo, const float* __restrict__ centroids,
    const float* __restrict__ asum, float* __restrict__ vp0,
    float* __restrict__ vp1)
{
    __shared__ f32x4 comb[4][64][4];
    __shared__ float asum_l[64];

    const int tid = threadIdx.x;
    const int w = tid >> 6, lane = tid & 63;
    const int wq = w & 3, wh = w >> 2;
    const int l15 = lane & 15, lg = lane >> 4;
    const int n = blockIdx.x, cp = blockIdx.y, sh = blockIdx.z;

    if (sh == 1 && tid < 64) asum_l[tid] = asum[n * Kk + tid];

    f32x4 zero4 = {0.f, 0.f, 0.f, 0.f};
    f32x4 acc[4] = {zero4, zero4, zero4, zero4};

    const int c = cp * 64 + 16 * wq + l15;
    const int sbase = sh * 512 + wh * 256;
    const float* xrow = x + (size_t)(n * Cc + c) * Ss + sbase;
    const short* ahb = a_hi + (size_t)n * Kk * Ss + sbase;
    const short* alb = a_lo + (size_t)n * Kk * Ss + sbase;

#pragma unroll 2
    for (int st = 0; st < 8; ++st) {
        const int so = st * 32 + 8 * lg;
        float4 xa = *(const float4*)&xrow[so];
        float4 xb = *(const float4*)&xrow[so + 4];
        float xv[8] = {xa.x, xa.y, xa.z, xa.w, xb.x, xb.y, xb.z, xb.w};
        FragU bh, bl;
        split8(xv, bh, bl);
#pragma unroll
        for (int m = 0; m < 4; ++m) {
            FragU ah, al;
            const size_t ao = (size_t)(16 * m + l15) * Ss + so;
            ah.u = *(const u32x4*)&ahb[ao];
            al.u = *(const u32x4*)&alb[ao];
            acc[m] = __builtin_amdgcn_mfma_f32_16x16x32_bf16(al.h, bh.h, acc[m], 0, 0, 0);
            acc[m] = __builtin_amdgcn_mfma_f32_16x16x32_bf16(ah.h, bl.h, acc[m], 0, 0, 0);
            acc[m] = __builtin_amdgcn_mfma_f32_16x16x32_bf16(ah.h, bh.h, acc[m], 0, 0, 0);
        }
    }

    if (wh == 1) {
#pragma unroll
        for (int m = 0; m < 4; ++m) comb[wq][lane][m] = acc[m];
    }
    __syncthreads();
    if (wh == 1) return;

    float* dst = sh ? vp1 : vp0;
#pragma unroll
    for (int m = 0; m < 4; ++m) {
        acc[m] += comb[wq][lane][m];
#pragma unroll
        for (int r = 0; r < 4; ++r) {
            const int k = 16 * m + 4 * lg + r;
            float val = acc[m][r];
            if (sh == 1) val -= asum_l[k] * centroids[(size_t)k * Cc + c];
            dst[(size_t)(n * Kk + k) * Cc + c] = val;
        }
    }
}

// ---------------------------------------------------------------------------
// K3a: vlad = vp0 + vp1 (in place into vp0) + per-row norm.
// grid (32 n, 8 kg), block 512: wave w owns row k = kg*8+w (512 c, coalesced).
// ---------------------------------------------------------------------------
__global__ __launch_bounds__(512) void k3a_norm(
    float* __restrict__ vlad, const float* __restrict__ vp1,
    float* __restrict__ nrm)
{
    const int tid = threadIdx.x;
    const int w = tid >> 6, lane = tid & 63;
    const int n = blockIdx.x, kg = blockIdx.y;
    const int row = (n * Kk) + kg * 8 + w;
    const size_t base = (size_t)row * Cc + lane * 8;

    float4 v0 = *(const float4*)&vlad[base];
    float4 v1 = *(const float4*)&vlad[base + 4];
    float4 u0 = *(const float4*)&vp1[base];
    float4 u1 = *(const float4*)&vp1[base + 4];
    v0.x += u0.x; v0.y += u0.y; v0.z += u0.z; v0.w += u0.w;
    v1.x += u1.x; v1.y += u1.y; v1.z += u1.z; v1.w += u1.w;
    *(float4*)&vlad[base] = v0;
    *(float4*)&vlad[base + 4] = v1;
    float ssq = v0.x*v0.x + v0.y*v0.y + v0.z*v0.z + v0.w*v0.w
              + v1.x*v1.x + v1.y*v1.y + v1.z*v1.z + v1.w*v1.w;
#pragma unroll
    for (int off = 32; off >= 1; off >>= 1) ssq += __shfl_xor(ssq, off);
    if (lane == 0) nrm[row] = sqrtf(ssq);
}

// ---------------------------------------------------------------------------
// K3b: scale[n][k] from nrm. grid 32, block 64.
// ---------------------------------------------------------------------------
__global__ __launch_bounds__(64) void k3b_scale(
    const float* __restrict__ nrm, float* __restrict__ scale)
{
    const int n = blockIdx.x, k = threadIdx.x;
    float r = nrm[n * Kk + k];
    float rn = r / fmaxf(r, 1e-12f);
    float p = rn * rn;
#pragma unroll
    for (int off = 32; off >= 1; off >>= 1) p += __shfl_xor(p, off);
    float g = sqrtf(p);
    scale[n * Kk + k] = 1.f / (fmaxf(r, 1e-12f) * fmaxf(g, 1e-12f));
}

// ---------------------------------------------------------------------------
// K4: partial v[n][d] over kc-chunk of 128 -> vpart[chunk][n][d].
// block 512 (8 waves): thread = (nq: 8 groups of 4 n) x (dq: 64 d, x4 dd).
// ---------------------------------------------------------------------------
__global__ __launch_bounds__(512) void k4_hidden(
    const float* __restrict__ vlad, const float* __restrict__ scale,
    const float* __restrict__ hw, float* __restrict__ vpart)
{
    __shared__ float vl[128][36];
    __shared__ float scale_l[32];
    const int tid = threadIdx.x;
    const int kc0 = blockIdx.x * 128;
    const int k = kc0 >> 9;
    if (tid < 32) scale_l[tid] = scale[tid * Kk + k];
    __syncthreads();
#pragma unroll
    for (int i = 0; i < 8; ++i) {
        int idx = tid + i * 512;
        int nn = idx >> 7, kcl = idx & 127;
        vl[kcl][nn] = vlad[(size_t)nn * (Kk * Cc) + kc0 + kcl] * scale_l[nn];
    }
    __syncthreads();

    const int dq = tid & 63, nq = tid >> 6;
    float acc[4][4];
#pragma unroll
    for (int i = 0; i < 4; ++i)
#pragma unroll
        for (int j = 0; j < 4; ++j) acc[i][j] = 0.f;

    for (int kcl = 0; kcl < 128; ++kcl) {
        const float4 v0 = *(const float4*)&vl[kcl][nq * 4];
        const float* wrow = &hw[(size_t)(kc0 + kcl) * Dd + dq];
#pragma unroll
        for (int dd = 0; dd < 4; ++dd) {
            float w = wrow[64 * dd];
            acc[dd][0] += w * v0.x; acc[dd][1] += w * v0.y;
            acc[dd][2] += w * v0.z; acc[dd][3] += w * v0.w;
        }
    }
#pragma unroll
    for (int dd = 0; dd < 4; ++dd)
#pragma unroll
        for (int j = 0; j < 4; ++j)
            vpart[((size_t)blockIdx.x * Nb + nq * 4 + j) * Dd + dq + 64 * dd] = acc[dd][j];
}

// ---------------------------------------------------------------------------
// K5a: reduce 256 partial chunks -> v[n][d]. grid 64 x 128.
// ---------------------------------------------------------------------------
__global__ __launch_bounds__(128) void k5a_reduce(
    const float* __restrict__ vpart, float* __restrict__ v)
{
    int flat = blockIdx.x * 128 + threadIdx.x;
    float s = 0.f;
#pragma unroll 8
    for (int ch = 0; ch < 256; ++ch) s += vpart[(size_t)ch * (Nb * Dd) + flat];
    v[flat] = s;
}

// ---------------------------------------------------------------------------
// K5b: BatchNorm over n (training stats, biased var, two-pass)
// ---------------------------------------------------------------------------
__global__ __launch_bounds__(256) void k5b_bn(
    const float* __restrict__ v, const float* __restrict__ gamma,
    const float* __restrict__ beta, float* __restrict__ v_bn)
{
    const int d = threadIdx.x;
    float vals[Nb];
    float s1 = 0.f;
#pragma unroll
    for (int n = 0; n < Nb; ++n) {
        vals[n] = v[n * Dd + d];
        s1 += vals[n];
    }
    float m = s1 * (1.f / Nb);
    float var = 0.f;
#pragma unroll
    for (int n = 0; n < Nb; ++n) {
        float t = vals[n] - m;
        var += t * t;
    }
    var *= (1.f / Nb);
    float inv = rsqrtf(var + 1e-5f);
    float g = gamma[d], b = beta[d];
#pragma unroll
    for (int n = 0; n < Nb; ++n)
        v_bn[n * Dd + d] = (vals[n] - m) * inv * g + b;
}

// ---------------------------------------------------------------------------
// K5c: g_raw = v_bn @ gating_w
// ---------------------------------------------------------------------------
__global__ __launch_bounds__(256) void k5c_gate(
    const float* __restrict__ v_bn, const float* __restrict__ gw,
    float* __restrict__ g_raw)
{
    __shared__ float vb[Dd];
    const int n = blockIdx.x, d = threadIdx.x;
    vb[d] = v_bn[n * Dd + d];
    __syncthreads();
    float acc = 0.f;
#pragma unroll 8
    for (int c = 0; c < Dd; ++c) acc += vb[c] * gw[c * Dd + d];
    g_raw[n * Dd + d] = acc;
}

// ---------------------------------------------------------------------------
// K5d: gbn BatchNorm + sigmoid + multiply -> out
// ---------------------------------------------------------------------------
__global__ __launch_bounds__(256) void k5d_out(
    const float* __restrict__ g_raw, const float* __restrict__ v_bn,
    const float* __restrict__ ggamma, const float* __restrict__ gbeta,
    float* __restrict__ out)
{
    const int d = threadIdx.x;
    float vals[Nb];
    float s1 = 0.f;
#pragma unroll
    for (int n = 0; n < Nb; ++n) {
        vals[n] = g_raw[n * Dd + d];
        s1 += vals[n];
    }
    float m = s1 * (1.f / Nb);
    float var = 0.f;
#pragma unroll
    for (int n = 0; n < Nb; ++n) {
        float t = vals[n] - m;
        var += t * t;
    }
    var *= (1.f / Nb);
    float inv = rsqrtf(var + 1e-5f);
    float g = ggamma[d], b = gbeta[d];
#pragma unroll
    for (int n = 0; n < Nb; ++n) {
        float t = (vals[n] - m) * inv * g + b;
        float sg = 1.f / (1.f + expf(-t));
        out[n * Dd + d] = v_bn[n * Dd + d] * sg;
    }
}

// ---------------------------------------------------------------------------
extern "C" void kernel_launch(void* const* d_in, const int* in_sizes, int n_in,
                              void* d_out, int out_size, void* d_ws, size_t ws_size,
                              hipStream_t stream)
{
    const float* x         = (const float*)d_in[0];
    const float* conv_w    = (const float*)d_in[1];
    const float* centroids = (const float*)d_in[2];
    const float* hidden_w  = (const float*)d_in[3];
    const float* bn2_gamma = (const float*)d_in[4];
    const float* bn2_beta  = (const float*)d_in[5];
    const float* gating_w  = (const float*)d_in[6];
    const float* gbn_gamma = (const float*)d_in[7];
    const float* gbn_beta  = (const float*)d_in[8];
    float* out = (float*)d_out;

    char* B = (char*)d_ws;
    short* a_hi      = (short*)(B);                          // 4 MB
    short* a_lo      = (short*)(B + (4u << 20));             // 4 MB
    float* vp0       = (float*)(B + (8u << 20));             // 4 MB (-> vlad)
    float* vp1       = (float*)(B + (12u << 20));            // 4 MB
    short* cw_hi     = (short*)(B + (16u << 20));            // 64 KB
    short* cw_lo     = (short*)(B + (16u << 20) + 65536u);   // 64 KB
    float* asum_part = (float*)(B + (16u << 20) + 131072u);  // 512 KB
    float* asum      = (float*)(B + (16u << 20) + 655360u);  // 8 KB
    float* nrm       = asum + 2048;                          // 8 KB
    float* scale     = nrm + 2048;
    float* v         = scale + 2048;
    float* v_bn      = v + 8192;
    float* g_raw     = v_bn + 8192;
    float* vpart     = (float*)B;   // alias a_hi/a_lo (dead after k2), 8 MB

    kprep_cw<<<32, 256, 0, stream>>>(conv_w, cw_hi, cw_lo);
    k1_sa<<<dim3(16, 32), 512, 0, stream>>>(x, cw_hi, cw_lo, a_hi, a_lo, asum_part);
    kasum<<<8, 256, 0, stream>>>(asum_part, asum);
    k2_vlad<<<dim3(32, 8, 2), 512, 0, stream>>>(x, a_hi, a_lo, centroids, asum, vp0, vp1);
    k3a_norm<<<dim3(32, 8), 512, 0, stream>>>(vp0, vp1, nrm);
    k3b_scale<<<32, 64, 0, stream>>>(nrm, scale);
    k4_hidden<<<256, 512, 0, stream>>>(vp0, scale, hidden_w, vpart);
    k5a_reduce<<<64, 128, 0, stream>>>(vpart, v);
    k5b_bn<<<1, 256, 0, stream>>>(v, bn2_gamma, bn2_beta, v_bn);
    k5c_gate<<<32, 256, 0, stream>>>(v_bn, gating_w, g_raw);
    k5d_out<<<1, 256, 0, stream>>>(g_raw, v_bn, gbn_gamma, gbn_beta, out);
}